// Round 1
// baseline (3291.796 us; speedup 1.0000x reference)
//
#include <hip/hip_runtime.h>

#define DD 128

// sizes (fixed by the problem, but read edge counts from in_sizes at launch)
constexpr int cN0 = 100000, cN1 = 50000, cN2 = 10000;
constexpr int cE1 = 1600000, cE2 = 320000;

// ---------------------------------------------------------------------------
// Edge-parallel SpMM: h_out[dst] += h_in[src] * ew, 32 lanes per edge,
// one float4 per lane (coalesced 512B row gather, contiguous atomics).
// ---------------------------------------------------------------------------
__global__ __launch_bounds__(256) void spmm_atomic_kernel(
    const float* __restrict__ h_in,
    const float* __restrict__ ew,
    const int* __restrict__ src,
    const int* __restrict__ dst,
    float* __restrict__ h_out,
    int nedges) {
  int gid = blockIdx.x * 256 + threadIdx.x;
  int e = gid >> 5;          // 32 threads per edge
  int lane = gid & 31;
  if (e >= nedges) return;

  int s = src[e];
  int d = dst[e];
  float w = ew[e];

  const float4* xin = reinterpret_cast<const float4*>(h_in + (size_t)s * DD);
  float4 v = xin[lane];

  float* outp = h_out + (size_t)d * DD + lane * 4;
  unsafeAtomicAdd(outp + 0, v.x * w);
  unsafeAtomicAdd(outp + 1, v.y * w);
  unsafeAtomicAdd(outp + 2, v.z * w);
  unsafeAtomicAdd(outp + 3, v.w * w);
}

// ---------------------------------------------------------------------------
// out[n, c] = dot(h[n, :], W[c, :]) + b[c]   (out = h @ W.T + b)
// 256 threads/block -> 2 rows per block, thread = (row_in_block, col).
// h rows staged in LDS; W reads served from L1/L2 (64 KB total).
// ---------------------------------------------------------------------------
__global__ __launch_bounds__(256) void linear_kernel(
    const float* __restrict__ h,
    const float* __restrict__ W,
    const float* __restrict__ b,
    float* __restrict__ out,
    int nrows) {
  __shared__ float hrow[2][DD];
  int row0 = blockIdx.x * 2;
  int t = threadIdx.x;

  int lr = t >> 7;       // 0 or 1: which of the 2 rows
  int c  = t & 127;      // column 0..127

  if (row0 + lr < nrows) hrow[lr][c] = h[(size_t)(row0 + lr) * DD + c];
  __syncthreads();

  int row = row0 + lr;
  if (row >= nrows) return;

  float acc = b[c];
  const float* wr = W + (size_t)c * DD;
  const float* hr = hrow[lr];
#pragma unroll 8
  for (int d = 0; d < DD; ++d) acc += hr[d] * wr[d];

  out[(size_t)row * DD + c] = acc;
}

extern "C" void kernel_launch(void* const* d_in, const int* in_sizes, int n_in,
                              void* d_out, int out_size, void* d_ws, size_t ws_size,
                              hipStream_t stream) {
  const float* x   = (const float*)d_in[0];
  const float* ew1 = (const float*)d_in[1];
  const float* ew2 = (const float*)d_in[2];
  const float* W   = (const float*)d_in[3];
  const float* b   = (const float*)d_in[4];
  const int* e1_src = (const int*)d_in[5];
  const int* e1_dst = (const int*)d_in[6];
  const int* e2_src = (const int*)d_in[7];
  const int* e2_dst = (const int*)d_in[8];
  float* out = (float*)d_out;

  int E1 = in_sizes[1];
  int E2 = in_sizes[2];

  // workspace layout: h1 [N1*D] floats, then h2 [N2*D] floats
  float* h1 = (float*)d_ws;
  float* h2 = h1 + (size_t)cN1 * DD;

  // zero accumulators every call (harness poisons ws once, never restores)
  hipMemsetAsync(h1, 0, (size_t)cN1 * DD * sizeof(float), stream);
  hipMemsetAsync(h2, 0, (size_t)cN2 * DD * sizeof(float), stream);

  // block 1: x [N0,D] -> h1 [N1,D]
  {
    long long total = (long long)E1 * 32;
    int grid = (int)((total + 255) / 256);
    spmm_atomic_kernel<<<grid, 256, 0, stream>>>(x, ew1, e1_src, e1_dst, h1, E1);
  }
  // block 2: h1 -> h2 [N2,D]
  {
    long long total = (long long)E2 * 32;
    int grid = (int)((total + 255) / 256);
    spmm_atomic_kernel<<<grid, 256, 0, stream>>>(h1, ew2, e2_src, e2_dst, h2, E2);
  }
  // linear: out = h2 @ W.T + b
  {
    int nrows = out_size / DD;  // N2
    int grid = (nrows + 1) / 2;
    linear_kernel<<<grid, 256, 0, stream>>>(h2, W, b, out, nrows);
  }
}

// Round 2
// 590.385 us; speedup vs baseline: 5.5757x; 5.5757x over previous
//
#include <hip/hip_runtime.h>

#define DD 128

constexpr int cN0 = 100000, cN1 = 50000, cN2 = 10000;

// ---------------------------------------------------------------------------
// CSR build step 1: histogram of dst (counts accumulated into `cnt`)
// ---------------------------------------------------------------------------
__global__ __launch_bounds__(256) void hist_kernel(
    const int* __restrict__ dst, int nedges, int* __restrict__ cnt) {
  int e = blockIdx.x * 256 + threadIdx.x;
  if (e < nedges) atomicAdd(&cnt[dst[e]], 1);
}

// ---------------------------------------------------------------------------
// CSR build step 2: single-block exclusive scan of cnt[0..n) -> ofs[0..n],
// and rewrite cnt in-place as the scatter cursors (== ofs[0..n)).
// ---------------------------------------------------------------------------
__global__ __launch_bounds__(1024) void scan_kernel(
    int* __restrict__ cnt, int n, int* __restrict__ ofs) {
  __shared__ int part[1024];
  int t = threadIdx.x;
  int chunk = (n + 1023) / 1024;
  int lo = t * chunk;
  int hi = lo + chunk; if (hi > n) hi = n;

  int s = 0;
  for (int i = lo; i < hi; ++i) s += cnt[i];
  part[t] = s;
  __syncthreads();
  for (int d = 1; d < 1024; d <<= 1) {
    int v = (t >= d) ? part[t - d] : 0;
    __syncthreads();
    part[t] += v;
    __syncthreads();
  }
  int run = (t == 0) ? 0 : part[t - 1];
  for (int i = lo; i < hi; ++i) {
    int c = cnt[i];          // read BEFORE overwrite (cnt doubles as cursor)
    ofs[i] = run;
    cnt[i] = run;
    run += c;
  }
  if (t == 1023) ofs[n] = part[1023];
}

// ---------------------------------------------------------------------------
// CSR build step 3: scatter (src, w) pairs into dst-sorted order.
// ---------------------------------------------------------------------------
__global__ __launch_bounds__(256) void scatter_kernel(
    const int* __restrict__ src, const int* __restrict__ dst,
    const float* __restrict__ ew, int nedges,
    int* __restrict__ cursor, int2* __restrict__ sorted) {
  int e = blockIdx.x * 256 + threadIdx.x;
  if (e >= nedges) return;
  int d = dst[e];
  int pos = atomicAdd(&cursor[d], 1);
  int2 pk;
  pk.x = src[e];
  pk.y = __float_as_int(ew[e]);
  sorted[pos] = pk;
}

// ---------------------------------------------------------------------------
// Gather-side SpMM: one wave per dst row. lane owns float2 (64*8B = 512B row).
// acc in registers, single coalesced write per row. No atomics.
// ---------------------------------------------------------------------------
__global__ __launch_bounds__(256) void spmm_csr_kernel(
    const float* __restrict__ h_in,
    const int* __restrict__ ofs,
    const int2* __restrict__ sorted,
    float* __restrict__ h_out,
    int nrows) {
  int wave = (blockIdx.x * 256 + threadIdx.x) >> 6;
  int lane = threadIdx.x & 63;
  if (wave >= nrows) return;

  int lo = ofs[wave];
  int hi = ofs[wave + 1];

  float2 acc = make_float2(0.f, 0.f);
  int j = lo;
  for (; j + 1 < hi; j += 2) {
    int2 e0 = sorted[j];
    int2 e1 = sorted[j + 1];
    const float2* p0 = reinterpret_cast<const float2*>(h_in + (size_t)e0.x * DD);
    const float2* p1 = reinterpret_cast<const float2*>(h_in + (size_t)e1.x * DD);
    float2 v0 = p0[lane];
    float2 v1 = p1[lane];
    float w0 = __int_as_float(e0.y);
    float w1 = __int_as_float(e1.y);
    acc.x += v0.x * w0 + v1.x * w1;
    acc.y += v0.y * w0 + v1.y * w1;
  }
  if (j < hi) {
    int2 e0 = sorted[j];
    const float2* p0 = reinterpret_cast<const float2*>(h_in + (size_t)e0.x * DD);
    float2 v0 = p0[lane];
    float w0 = __int_as_float(e0.y);
    acc.x += v0.x * w0;
    acc.y += v0.y * w0;
  }

  reinterpret_cast<float2*>(h_out + (size_t)wave * DD)[lane] = acc;
}

// ---------------------------------------------------------------------------
// out[n, c] = dot(h[n, :], W[c, :]) + b[c]
// ---------------------------------------------------------------------------
__global__ __launch_bounds__(256) void linear_kernel(
    const float* __restrict__ h,
    const float* __restrict__ W,
    const float* __restrict__ b,
    float* __restrict__ out,
    int nrows) {
  __shared__ float hrow[2][DD];
  int row0 = blockIdx.x * 2;
  int t = threadIdx.x;
  int lr = t >> 7;
  int c  = t & 127;

  if (row0 + lr < nrows) hrow[lr][c] = h[(size_t)(row0 + lr) * DD + c];
  __syncthreads();

  int row = row0 + lr;
  if (row >= nrows) return;

  float acc = b[c];
  const float* wr = W + (size_t)c * DD;
  const float* hr = hrow[lr];
#pragma unroll 8
  for (int d = 0; d < DD; ++d) acc += hr[d] * wr[d];

  out[(size_t)row * DD + c] = acc;
}

static inline size_t align256(size_t x) { return (x + 255) & ~size_t(255); }

extern "C" void kernel_launch(void* const* d_in, const int* in_sizes, int n_in,
                              void* d_out, int out_size, void* d_ws, size_t ws_size,
                              hipStream_t stream) {
  const float* x   = (const float*)d_in[0];
  const float* ew1 = (const float*)d_in[1];
  const float* ew2 = (const float*)d_in[2];
  const float* W   = (const float*)d_in[3];
  const float* b   = (const float*)d_in[4];
  const int* e1_src = (const int*)d_in[5];
  const int* e1_dst = (const int*)d_in[6];
  const int* e2_src = (const int*)d_in[7];
  const int* e2_dst = (const int*)d_in[8];
  float* out = (float*)d_out;

  int E1 = in_sizes[1];
  int E2 = in_sizes[2];

  // ---- workspace layout ----
  char* p = (char*)d_ws;
  float* h1 = (float*)p;              p += align256((size_t)cN1 * DD * 4);
  float* h2 = (float*)p;              p += align256((size_t)cN2 * DD * 4);
  int* ofs1 = (int*)p;                p += align256((size_t)(cN1 + 1) * 4);
  int* cur1 = (int*)p;                p += align256((size_t)cN1 * 4);
  int* ofs2 = (int*)p;                p += align256((size_t)(cN2 + 1) * 4);
  int* cur2 = (int*)p;                p += align256((size_t)cN2 * 4);
  int2* sorted1 = (int2*)p;           p += align256((size_t)E1 * 8);
  int2* sorted2 = (int2*)p;           p += align256((size_t)E2 * 8);

  // ---- CSR build for both blocks ----
  hipMemsetAsync(cur1, 0, (size_t)cN1 * 4, stream);
  hipMemsetAsync(cur2, 0, (size_t)cN2 * 4, stream);

  hist_kernel<<<(E1 + 255) / 256, 256, 0, stream>>>(e1_dst, E1, cur1);
  hist_kernel<<<(E2 + 255) / 256, 256, 0, stream>>>(e2_dst, E2, cur2);

  scan_kernel<<<1, 1024, 0, stream>>>(cur1, cN1, ofs1);
  scan_kernel<<<1, 1024, 0, stream>>>(cur2, cN2, ofs2);

  scatter_kernel<<<(E1 + 255) / 256, 256, 0, stream>>>(e1_src, e1_dst, ew1, E1, cur1, sorted1);
  scatter_kernel<<<(E2 + 255) / 256, 256, 0, stream>>>(e2_src, e2_dst, ew2, E2, cur2, sorted2);

  // ---- SpMM block 1: x -> h1 ----
  {
    int waves_per_block = 4;  // 256 threads
    int grid = (cN1 + waves_per_block - 1) / waves_per_block;
    spmm_csr_kernel<<<grid, 256, 0, stream>>>(x, ofs1, sorted1, h1, cN1);
  }
  // ---- SpMM block 2: h1 -> h2 ----
  {
    int waves_per_block = 4;
    int grid = (cN2 + waves_per_block - 1) / waves_per_block;
    spmm_csr_kernel<<<grid, 256, 0, stream>>>(h1, ofs2, sorted2, h2, cN2);
  }
  // ---- linear: out = h2 @ W.T + b ----
  {
    int nrows = out_size / DD;
    int grid = (nrows + 1) / 2;
    linear_kernel<<<grid, 256, 0, stream>>>(h2, W, b, out, nrows);
  }
}

// Round 3
// 390.608 us; speedup vs baseline: 8.4274x; 1.5115x over previous
//
#include <hip/hip_runtime.h>

#define DD 128

constexpr int cN1 = 50000, cN2 = 10000;

// ---------------------------------------------------------------------------
// CSR build step 1: histogram of dst AND per-edge rank within its dst.
// ---------------------------------------------------------------------------
__global__ __launch_bounds__(256) void hist_rank_kernel(
    const int* __restrict__ dst, int nedges,
    int* __restrict__ cnt, int* __restrict__ rank) {
  int e = blockIdx.x * 256 + threadIdx.x;
  if (e < nedges) rank[e] = atomicAdd(&cnt[dst[e]], 1);
}

// ---------------------------------------------------------------------------
// CSR build step 2a: per-1024-chunk exclusive scan (local) -> ofs,
// chunk totals -> bsum. 256 threads, 4 elements each.
// ---------------------------------------------------------------------------
__global__ __launch_bounds__(256) void scan_blk_kernel(
    const int* __restrict__ cnt, int n,
    int* __restrict__ ofs, int* __restrict__ bsum) {
  __shared__ int tsum[256];
  int t = threadIdx.x;
  int base = blockIdx.x * 1024 + t * 4;
  int v0 = (base     < n) ? cnt[base]     : 0;
  int v1 = (base + 1 < n) ? cnt[base + 1] : 0;
  int v2 = (base + 2 < n) ? cnt[base + 2] : 0;
  int v3 = (base + 3 < n) ? cnt[base + 3] : 0;
  tsum[t] = v0 + v1 + v2 + v3;
  __syncthreads();
  for (int d = 1; d < 256; d <<= 1) {
    int x = (t >= d) ? tsum[t - d] : 0;
    __syncthreads();
    tsum[t] += x;
    __syncthreads();
  }
  int ex = (t == 0) ? 0 : tsum[t - 1];
  if (base     < n) ofs[base]     = ex;
  if (base + 1 < n) ofs[base + 1] = ex + v0;
  if (base + 2 < n) ofs[base + 2] = ex + v0 + v1;
  if (base + 3 < n) ofs[base + 3] = ex + v0 + v1 + v2;
  if (t == 255) bsum[blockIdx.x] = tsum[255];
}

// ---------------------------------------------------------------------------
// CSR build step 2b: wave-scan of chunk sums (nb <= 64), bsum -> exclusive,
// and write grand total to ofs[n].
// ---------------------------------------------------------------------------
__global__ __launch_bounds__(64) void scan_bsum_kernel(
    int* __restrict__ bsum, int nb, int* __restrict__ ofs, int n) {
  int t = threadIdx.x;
  int orig = (t < nb) ? bsum[t] : 0;
  int v = orig;
  for (int d = 1; d < 64; d <<= 1) {
    int u = __shfl_up(v, d);
    if (t >= d) v += u;
  }
  if (t < nb) bsum[t] = v - orig;   // exclusive
  if (t == 63) ofs[n] = v;          // grand total
}

// ---------------------------------------------------------------------------
// CSR build step 2c: add chunk base offsets in place.
// ---------------------------------------------------------------------------
__global__ __launch_bounds__(256) void scan_add_kernel(
    int* __restrict__ ofs, int n, const int* __restrict__ bsum) {
  int i = blockIdx.x * 256 + threadIdx.x;
  if (i < n) ofs[i] += bsum[i >> 10];
}

// ---------------------------------------------------------------------------
// CSR build step 3: scatter (src, w) pairs into dst-sorted order.
// No atomics: pos = ofs[dst] + rank. All reads sequential.
// ---------------------------------------------------------------------------
__global__ __launch_bounds__(256) void scatter_kernel(
    const int* __restrict__ src, const int* __restrict__ dst,
    const float* __restrict__ ew, const int* __restrict__ rank,
    const int* __restrict__ ofs, int nedges,
    unsigned long long* __restrict__ sorted) {
  int e = blockIdx.x * 256 + threadIdx.x;
  if (e >= nedges) return;
  int pos = ofs[dst[e]] + rank[e];
  unsigned long long pk =
      (unsigned long long)(unsigned int)src[e] |
      ((unsigned long long)(unsigned int)__float_as_uint(ew[e]) << 32);
  __builtin_nontemporal_store(pk, sorted + pos);
}

// ---------------------------------------------------------------------------
// Gather-side SpMM: one wave per dst row, lane owns float2 (64*8B = 512B row).
// Unroll 8: 8 independent row-gathers in flight per wave.
// ---------------------------------------------------------------------------
__global__ __launch_bounds__(256) void spmm_csr_kernel(
    const float* __restrict__ h_in,
    const int* __restrict__ ofs,
    const unsigned long long* __restrict__ sorted,
    float* __restrict__ h_out,
    int nrows) {
  int wave = (blockIdx.x * 256 + threadIdx.x) >> 6;
  int lane = threadIdx.x & 63;
  if (wave >= nrows) return;

  int lo = ofs[wave];
  int hi = ofs[wave + 1];

  float accx = 0.f, accy = 0.f;
  int j = lo;

#define GATHER(P, VX, VY)                                                    \
  {                                                                          \
    int s_ = (int)(unsigned int)(P);                                         \
    const float2* pr_ = reinterpret_cast<const float2*>(h_in + (size_t)s_ * DD); \
    float2 v_ = pr_[lane];                                                   \
    float w_ = __uint_as_float((unsigned int)((P) >> 32));                   \
    VX += v_.x * w_;                                                         \
    VY += v_.y * w_;                                                         \
  }

  float ax1 = 0.f, ay1 = 0.f;  // second accumulator pair for ILP
  for (; j + 8 <= hi; j += 8) {
    unsigned long long p0 = __builtin_nontemporal_load(sorted + j);
    unsigned long long p1 = __builtin_nontemporal_load(sorted + j + 1);
    unsigned long long p2 = __builtin_nontemporal_load(sorted + j + 2);
    unsigned long long p3 = __builtin_nontemporal_load(sorted + j + 3);
    unsigned long long p4 = __builtin_nontemporal_load(sorted + j + 4);
    unsigned long long p5 = __builtin_nontemporal_load(sorted + j + 5);
    unsigned long long p6 = __builtin_nontemporal_load(sorted + j + 6);
    unsigned long long p7 = __builtin_nontemporal_load(sorted + j + 7);
    GATHER(p0, accx, accy) GATHER(p1, ax1, ay1)
    GATHER(p2, accx, accy) GATHER(p3, ax1, ay1)
    GATHER(p4, accx, accy) GATHER(p5, ax1, ay1)
    GATHER(p6, accx, accy) GATHER(p7, ax1, ay1)
  }
  for (; j + 2 <= hi; j += 2) {
    unsigned long long p0 = __builtin_nontemporal_load(sorted + j);
    unsigned long long p1 = __builtin_nontemporal_load(sorted + j + 1);
    GATHER(p0, accx, accy) GATHER(p1, ax1, ay1)
  }
  if (j < hi) {
    unsigned long long p0 = __builtin_nontemporal_load(sorted + j);
    GATHER(p0, accx, accy)
  }
#undef GATHER

  float2 out;
  out.x = accx + ax1;
  out.y = accy + ay1;
  reinterpret_cast<float2*>(h_out + (size_t)wave * DD)[lane] = out;
}

// ---------------------------------------------------------------------------
// out[n, c] = dot(h[n, :], W[c, :]) + b[c]
// ---------------------------------------------------------------------------
__global__ __launch_bounds__(256) void linear_kernel(
    const float* __restrict__ h,
    const float* __restrict__ W,
    const float* __restrict__ b,
    float* __restrict__ out,
    int nrows) {
  __shared__ float hrow[2][DD];
  int row0 = blockIdx.x * 2;
  int t = threadIdx.x;
  int lr = t >> 7;
  int c  = t & 127;

  if (row0 + lr < nrows) hrow[lr][c] = h[(size_t)(row0 + lr) * DD + c];
  __syncthreads();

  int row = row0 + lr;
  if (row >= nrows) return;

  float acc = b[c];
  const float* wr = W + (size_t)c * DD;
  const float* hr = hrow[lr];
#pragma unroll 8
  for (int d = 0; d < DD; ++d) acc += hr[d] * wr[d];

  out[(size_t)row * DD + c] = acc;
}

static inline size_t align256(size_t x) { return (x + 255) & ~size_t(255); }

extern "C" void kernel_launch(void* const* d_in, const int* in_sizes, int n_in,
                              void* d_out, int out_size, void* d_ws, size_t ws_size,
                              hipStream_t stream) {
  const float* x   = (const float*)d_in[0];
  const float* ew1 = (const float*)d_in[1];
  const float* ew2 = (const float*)d_in[2];
  const float* W   = (const float*)d_in[3];
  const float* b   = (const float*)d_in[4];
  const int* e1_src = (const int*)d_in[5];
  const int* e1_dst = (const int*)d_in[6];
  const int* e2_src = (const int*)d_in[7];
  const int* e2_dst = (const int*)d_in[8];
  float* out = (float*)d_out;

  int E1 = in_sizes[1];
  int E2 = in_sizes[2];

  int nb1 = (cN1 + 1023) / 1024;  // 49
  int nb2 = (cN2 + 1023) / 1024;  // 10

  // ---- workspace layout ----
  char* p = (char*)d_ws;
  float* h1 = (float*)p;                  p += align256((size_t)cN1 * DD * 4);
  float* h2 = (float*)p;                  p += align256((size_t)cN2 * DD * 4);
  int* cnt1 = (int*)p;                    p += align256((size_t)cN1 * 4);
  int* cnt2 = (int*)p;                    p += align256((size_t)cN2 * 4);
  int* ofs1 = (int*)p;                    p += align256((size_t)(cN1 + 1) * 4);
  int* ofs2 = (int*)p;                    p += align256((size_t)(cN2 + 1) * 4);
  int* bsum1 = (int*)p;                   p += align256(64 * 4);
  int* bsum2 = (int*)p;                   p += align256(64 * 4);
  int* rank1 = (int*)p;                   p += align256((size_t)E1 * 4);
  int* rank2 = (int*)p;                   p += align256((size_t)E2 * 4);
  unsigned long long* sorted1 = (unsigned long long*)p;  p += align256((size_t)E1 * 8);
  unsigned long long* sorted2 = (unsigned long long*)p;  p += align256((size_t)E2 * 8);

  // zero the histograms (only state that needs zeroing each call)
  hipMemsetAsync(cnt1, 0, (size_t)cN1 * 4, stream);
  hipMemsetAsync(cnt2, 0, (size_t)cN2 * 4, stream);

  // ---- CSR build, graph 1 & 2 ----
  hist_rank_kernel<<<(E1 + 255) / 256, 256, 0, stream>>>(e1_dst, E1, cnt1, rank1);
  hist_rank_kernel<<<(E2 + 255) / 256, 256, 0, stream>>>(e2_dst, E2, cnt2, rank2);

  scan_blk_kernel<<<nb1, 256, 0, stream>>>(cnt1, cN1, ofs1, bsum1);
  scan_blk_kernel<<<nb2, 256, 0, stream>>>(cnt2, cN2, ofs2, bsum2);
  scan_bsum_kernel<<<1, 64, 0, stream>>>(bsum1, nb1, ofs1, cN1);
  scan_bsum_kernel<<<1, 64, 0, stream>>>(bsum2, nb2, ofs2, cN2);
  scan_add_kernel<<<(cN1 + 255) / 256, 256, 0, stream>>>(ofs1, cN1, bsum1);
  scan_add_kernel<<<(cN2 + 255) / 256, 256, 0, stream>>>(ofs2, cN2, bsum2);

  scatter_kernel<<<(E1 + 255) / 256, 256, 0, stream>>>(e1_src, e1_dst, ew1, rank1, ofs1, E1, sorted1);
  scatter_kernel<<<(E2 + 255) / 256, 256, 0, stream>>>(e2_src, e2_dst, ew2, rank2, ofs2, E2, sorted2);

  // ---- SpMM block 1: x -> h1 ----
  spmm_csr_kernel<<<(cN1 + 3) / 4, 256, 0, stream>>>(x, ofs1, sorted1, h1, cN1);
  // ---- SpMM block 2: h1 -> h2 ----
  spmm_csr_kernel<<<(cN2 + 3) / 4, 256, 0, stream>>>(h1, ofs2, sorted2, h2, cN2);

  // ---- linear: out = h2 @ W.T + b ----
  {
    int nrows = out_size / DD;
    int grid = (nrows + 1) / 2;
    linear_kernel<<<grid, 256, 0, stream>>>(h2, W, b, out, nrows);
  }
}